// Round 6
// baseline (214.972 us; speedup 1.0000x reference)
//
#include <hip/hip_runtime.h>
#include <stdint.h>

// Problem constants (fixed by the reference setup)
#define BB 2
#define NN 10000
#define EE 100000
#define FF 512
#define HH 512
constexpr int M_ROWS = BB * NN;   // 20000 GEMM rows
constexpr int M_PAD  = 20160;     // padded to multiple of 160 (126 blocks/sel)
constexpr int BE     = BB * EE;   // 200000 edges total
constexpr int BNN    = BB * NN;   // 20000 segments

typedef __attribute__((ext_vector_type(8))) short short8;   // 8 bf16 (4 VGPRs)
typedef __attribute__((ext_vector_type(4))) float f32x4;    // MFMA accumulator
typedef __attribute__((ext_vector_type(2))) float f32x2;
typedef _Float16 half2v __attribute__((ext_vector_type(2)));

#define AS1 __attribute__((address_space(1)))
#define AS3 __attribute__((address_space(3)))

__device__ __forceinline__ float b2f(unsigned short u) {
    union { unsigned int i; float f; } v; v.i = ((unsigned int)u) << 16; return v.f;
}
__device__ __forceinline__ unsigned short f2b(float f) {   // round-to-nearest-even
    unsigned int x = __float_as_uint(f);
    x += 0x7fffu + ((x >> 16) & 1u);
    return (unsigned short)(x >> 16);
}
__device__ __forceinline__ unsigned char f2fp8(float v) {
    unsigned int p = __builtin_amdgcn_cvt_pk_fp8_f32(v, v, 0u, false);
    return (unsigned char)(p & 0xffu);
}
__device__ __forceinline__ half2v uint2h2(unsigned int u) {
    union { unsigned int u; half2v h; } v; v.u = u; return v.h;
}

// fp8(e4m3) pair -> f16 pair. sel=false: bytes[1:0], sel=true: bytes[3:2].
#if __has_builtin(__builtin_amdgcn_cvt_scalef32_pk_f16_fp8)
  #define CVT8H(u, sel) __builtin_amdgcn_cvt_scalef32_pk_f16_fp8((u), 1.0f, (sel))
#else
  #define CVT8H(u, sel) ({ f32x2 _p = __builtin_amdgcn_cvt_pk_f32_fp8((u), (sel)); \
                           (half2v){(_Float16)_p.x, (_Float16)_p.y}; })
#endif

#if __has_builtin(__builtin_amdgcn_fdot2)
  #define FDOT2(a, b, c) __builtin_amdgcn_fdot2((a), (b), (c), false)
#else
  #define FDOT2(a, b, c) ((float)(a).x * (float)(b).x + (float)(a).y * (float)(b).y + (c))
#endif

// ---------------- fused front-end: detect + convertX + transpose + params + zero ------
// One dispatch replaces five. Every block recomputes the dtype flag inline (reads
// 510 B of X, wave-0 shuffle reduce -> LDS broadcast): no cross-dispatch dependency.
// Block ranges:  [0,5000)   convertX (f32 path only; early-exit when input is bf16)
//                [5000,5512) W1/W2 transpose (32x32 tiles, 2 mats)
//                [5512,5529) param canonicalization (P layout below)
//                [5529,5686) zero segment-sum buffer
// P layout (ushort): b1@0 g1@512 bb1@1024 b2@1536 g2@2048 bb2@2560 W3(bf16)@3072
// W4@3584 b4@3585 | W3(f16)@3600..4111
constexpr int PREP_CX = 5000;
constexpr int PREP_TR = PREP_CX + 512;
constexpr int PREP_CP = PREP_TR + 17;
constexpr int PREP_NB = PREP_CP + 157;
__global__ __launch_bounds__(256) void prep_k(
    const void* __restrict__ Xraw,
    const void* __restrict__ W1, const void* __restrict__ W2,
    const void* b1, const void* g1, const void* bb1,
    const void* b2, const void* g2, const void* bb2,
    const void* W3, const void* W4, const void* b4,
    int* __restrict__ flag, unsigned short* __restrict__ Xb,
    unsigned short* __restrict__ T1, unsigned short* __restrict__ T2,
    unsigned short* __restrict__ P, float* __restrict__ Z)
{
    __shared__ int sflag;
    __shared__ unsigned short t[32][33];
    const int tid = threadIdx.x;
    const int bid = blockIdx.x;

    if (tid < 64) {                       // wave 0: dtype detect (same rule as before)
        const unsigned short* x = (const unsigned short*)Xraw;
        int good = 0;
#pragma unroll
        for (int j = 0; j < 2; j++) {
            unsigned short u = x[2 * (tid * 2 + j)];
            int e = (u >> 7) & 0xFF;
            if (e >= 100 && e <= 140) good++;
        }
#pragma unroll
        for (int off = 32; off >= 1; off >>= 1) good += __shfl_xor(good, off, 64);
        if (tid == 0) sflag = (good < 96) ? 1 : 0;
    }
    __syncthreads();
    const int isf = sflag;
    if (bid == 0 && tid == 0) *flag = isf;

    if (bid < PREP_CX) {                  // ---- convertX: only needed for f32 input
        if (!isf) return;                 // bf16 input: gemm reads X_raw directly
        int i = (bid * 256 + tid) * 8;
        if (i >= M_ROWS * 512) return;
        const float4* f = (const float4*)((const float*)Xraw + i);
        float4 a = f[0], b = f[1];
        short8 o;
        o[0] = (short)f2b(a.x); o[1] = (short)f2b(a.y);
        o[2] = (short)f2b(a.z); o[3] = (short)f2b(a.w);
        o[4] = (short)f2b(b.x); o[5] = (short)f2b(b.y);
        o[6] = (short)f2b(b.z); o[7] = (short)f2b(b.w);
        *(short8*)(Xb + i) = o;
        return;
    }
    if (bid < PREP_TR) {                  // ---- transpose W -> WT[n][k]
        int b2i = bid - PREP_CX;
        int bx = b2i & 15, by = (b2i >> 4) & 15, bz = b2i >> 8;
        const void*     W = bz ? W2 : W1;
        unsigned short* T = bz ? T2 : T1;
        int tx = tid & 31, ty = tid >> 5;   // 32 x 8
        int n0 = bx * 32, k0 = by * 32;
#pragma unroll
        for (int r = 0; r < 4; r++) {
            int k = k0 + ty + r * 8;
            unsigned short v;
            if (isf) v = f2b(((const float*)W)[k * 512 + n0 + tx]);
            else     v = ((const unsigned short*)W)[k * 512 + n0 + tx];
            t[ty + r * 8][tx] = v;
        }
        __syncthreads();
#pragma unroll
        for (int r = 0; r < 4; r++) {
            int n = n0 + ty + r * 8;
            T[n * 512 + k0 + tx] = t[tx][ty + r * 8];
        }
        return;
    }
    if (bid < PREP_CP) {                  // ---- small params
        int i = (bid - PREP_TR) * 256 + tid;
        if (i >= 4098) return;
        if (i >= 3586) {                  // W3 -> f16 copy for edge_k dot2
            int j = i - 3586;             // 0..511
            float f;
            if (isf) f = ((const float*)W3)[j];
            else     f = b2f(((const unsigned short*)W3)[j]);
            union { _Float16 h; unsigned short u; } cv;
            cv.h = (_Float16)f;
            P[3600 + j] = cv.u;
            return;
        }
        const void* src; int off;
        if      (i < 512)  { src = b1;  off = i; }
        else if (i < 1024) { src = g1;  off = i - 512; }
        else if (i < 1536) { src = bb1; off = i - 1024; }
        else if (i < 2048) { src = b2;  off = i - 1536; }
        else if (i < 2560) { src = g2;  off = i - 2048; }
        else if (i < 3072) { src = bb2; off = i - 2560; }
        else if (i < 3584) { src = W3;  off = i - 3072; }
        else if (i == 3584){ src = W4;  off = 0; }
        else               { src = b4;  off = 0; }
        unsigned short v;
        if (isf) v = f2b(((const float*)src)[off]);
        else     v = ((const unsigned short*)src)[off];
        P[i] = v;
        return;
    }
    {                                     // ---- zero segment sums
        int i = (bid - PREP_CP) * 256 + tid;
        if (i < 2 * BNN) Z[i] = 0.f;
    }
}

// ---------------- fused GEMM (X @ W) + bias + LayerNorm -> a12 (fp8 e4m3) ----------------
// v11: K-stagger REVERTED (R5: same-address lockstep fetch is an L2 broadcast WIN, not a
// convoy -- stagger cost +23us). Transport A/B test: v9's per-iter cost matched
// 42 global_load_lds wave-instrs x ~200cyc L2 latency each (near-serial DMA per CU).
// v11 replaces the DMA with reg-staging: plain global loads (deeply pipelined by the
// compiler, many outstanding) issued at iter top for chunk it+1, ds_write after the
// MFMA block. All waits are compiler-managed counted vmcnt; manual drains removed.
// Double-buffered LDS (A 2x10KB, B 2x32KB = 84KB + 5KB red), ONE barrier per iter.
// B-fragment reads split into two halves reusing 4 regs (-16 VGPR) to offset the
// +24 staging VGPRs. Same LDS layout/swizzle as v9 on both write and read sides.
__global__ __launch_bounds__(512, 2) void gemm_ln11_k(
    const unsigned short* __restrict__ Xraw,  // raw input viewed as ushort (bf16 path)
    const unsigned short* __restrict__ Xb,    // canonical bf16 (f32 path)
    const int* __restrict__ flagp,
    const unsigned short* __restrict__ WT1,   // 512(n) x 512(k)  (pre-transposed bf16)
    const unsigned short* __restrict__ WT2,
    const unsigned short* __restrict__ bia1, const unsigned short* __restrict__ gg1, const unsigned short* __restrict__ sh1,
    const unsigned short* __restrict__ bia2, const unsigned short* __restrict__ gg2, const unsigned short* __restrict__ sh2,
    unsigned char* __restrict__ a12)          // 20000 x 1024 fp8 (a1 | a2)
{
    __shared__ __align__(16) unsigned short S[43008];  // 84 KB: A 2x10240B @0, B 2x32768B @20480; epilogue reuses as 160x528 byte tile
    __shared__ float red[160][4][2];

    const int sel = blockIdx.y;
    const unsigned short* WT  = sel ? WT2 : WT1;
    const unsigned short* bia = sel ? bia2 : bia1;
    const unsigned short* gg  = sel ? gg2 : gg1;
    const unsigned short* sh  = sel ? sh2 : sh1;
    const int r0   = blockIdx.x * 160;
    const int tid  = threadIdx.x;
    const int lane = tid & 63;
    const int w    = tid >> 6;      // 0..7
    const int mg   = w >> 2;        // 0..1  (80-row group)
    const int ng   = w & 3;         // 0..3  (128-col group)
    const int aq   = lane >> 4;     // 0..3
    const int l15  = lane & 15;

    const unsigned short* Xsrc = (*flagp) ? Xb : Xraw;

    AS3 char* S3 = (AS3 char*)S;
    const unsigned sb = (unsigned)(unsigned long long)S3;
    char* Sb = (char*)S;

    f32x4 acc[5][8];
#pragma unroll
    for (int i = 0; i < 5; i++)
#pragma unroll
        for (int j = 0; j < 8; j++) acc[i][j] = (f32x4){0.f, 0.f, 0.f, 0.f};

    // A staging: 640 slots (16B each). slot sid: r = sid>>2, kc = sid&3 (XOR-swizzled).
    // threads 0..511 take sid = tid; threads 0..127 (waves 0-1) also take sid = 512+tid.
    // Global row clamped to M_ROWS-1 (pad rows duplicate row 19999; stores masked).
    const int a_r1 = tid >> 2;
    const int a_k1 = (tid & 3) ^ ((a_r1 >> 1) & 3);
    int r1c = r0 + a_r1; if (r1c > M_ROWS - 1) r1c = M_ROWS - 1;
    const unsigned short* a_g1 = Xsrc + (size_t)r1c * 512 + a_k1 * 8;
    const int a_r2 = 128 + (tid >> 2);
    const int a_k2 = (tid & 3) ^ ((a_r2 >> 1) & 3);
    int r2c = r0 + a_r2; if (r2c > M_ROWS - 1) r2c = M_ROWS - 1;
    const unsigned short* a_g2 = Xsrc + (size_t)r2c * 512 + a_k2 * 8;
    // B staging: 2048 slots, 4/thread: n = u*128 + (tid>>2), kc = tid&3 (XOR-pre-swizzled
    // on the global side so the LDS image matches the swizzled read addresses)
    const int b_n0 = tid >> 2;
    const int b_kc = tid & 3;
    int bgo0, bgo1, bgo2, bgo3;
    { int n0_ = 0 * 128 + b_n0; bgo0 = n0_ * 512 + (b_kc ^ ((n0_ >> 1) & 3)) * 8; }
    { int n1_ = 1 * 128 + b_n0; bgo1 = n1_ * 512 + (b_kc ^ ((n1_ >> 1) & 3)) * 8; }
    { int n2_ = 2 * 128 + b_n0; bgo2 = n2_ * 512 + (b_kc ^ ((n2_ >> 1) & 3)) * 8; }
    { int n3_ = 3 * 128 + b_n0; bgo3 = n3_ * 512 + (b_kc ^ ((n3_ >> 1) & 3)) * 8; }

    // ---- prologue: stage chunk 0 (loads -> regs -> LDS buf0) ----
    {
        short8 aS0 = *(const short8*)(a_g1);
        short8 aS1 = {};
        if (tid < 128) aS1 = *(const short8*)(a_g2);
        short8 bS0 = *(const short8*)(WT + bgo0);
        short8 bS1 = *(const short8*)(WT + bgo1);
        short8 bS2 = *(const short8*)(WT + bgo2);
        short8 bS3 = *(const short8*)(WT + bgo3);
        *(short8*)(Sb + tid * 16) = aS0;
        if (tid < 128) *(short8*)(Sb + (512 + tid) * 16) = aS1;
        char* Bp = Sb + 20480;
        *(short8*)(Bp + (0 * 512 + tid) * 16) = bS0;
        *(short8*)(Bp + (1 * 512 + tid) * 16) = bS1;
        *(short8*)(Bp + (2 * 512 + tid) * 16) = bS2;
        *(short8*)(Bp + (3 * 512 + tid) * 16) = bS3;
    }

    for (int it = 0; it < 16; ++it) {
        __syncthreads();   // buf(it&1) writes visible; all prior reads of buf((it+1)&1) done

        // issue next chunk's global loads first: latency hides under ds_read + MFMA
        short8 aS0, aS1, bS0, bS1, bS2, bS3;
        const bool have = (it + 1 < 16);
        if (have) {
            const int k0n = (it + 1) * 32;
            aS0 = *(const short8*)(a_g1 + k0n);
            if (tid < 128) aS1 = *(const short8*)(a_g2 + k0n);
            bS0 = *(const short8*)(WT + bgo0 + k0n);
            bS1 = *(const short8*)(WT + bgo1 + k0n);
            bS2 = *(const short8*)(WT + bgo2 + k0n);
            bS3 = *(const short8*)(WT + bgo3 + k0n);
        }

        const unsigned Ab = sb + (unsigned)((it & 1) * 10240);
        const unsigned Bb = sb + 20480u + (unsigned)((it & 1) * 32768);
        short8 af[5], bf[4];
#pragma unroll
        for (int mt = 0; mt < 5; mt++) {
            int m = mg * 80 + mt * 16 + l15;
            unsigned off = Ab + (unsigned)(m * 64 + (aq ^ ((m >> 1) & 3)) * 16);
            asm volatile("ds_read_b128 %0, %1" : "=v"(af[mt]) : "v"(off));
        }
#pragma unroll
        for (int nt = 0; nt < 4; nt++) {
            int n = ng * 128 + nt * 16 + l15;
            unsigned off = Bb + (unsigned)(n * 64 + (aq ^ ((n >> 1) & 3)) * 16);
            asm volatile("ds_read_b128 %0, %1" : "=v"(bf[nt]) : "v"(off));
        }
        asm volatile("s_waitcnt lgkmcnt(0)"
                     : "+v"(af[0]), "+v"(af[1]), "+v"(af[2]), "+v"(af[3]), "+v"(af[4]),
                       "+v"(bf[0]), "+v"(bf[1]), "+v"(bf[2]), "+v"(bf[3]) :: "memory");
#pragma unroll
        for (int nt = 0; nt < 4; nt++)
#pragma unroll
            for (int mt = 0; mt < 5; mt++)
                acc[mt][nt] = __builtin_amdgcn_mfma_f32_16x16x32_bf16(af[mt], bf[nt], acc[mt][nt], 0, 0, 0);
#pragma unroll
        for (int nt = 4; nt < 8; nt++) {   // second half reuses bf[0..3]
            int n = ng * 128 + nt * 16 + l15;
            unsigned off = Bb + (unsigned)(n * 64 + (aq ^ ((n >> 1) & 3)) * 16);
            asm volatile("ds_read_b128 %0, %1" : "=v"(bf[nt - 4]) : "v"(off));
        }
        asm volatile("s_waitcnt lgkmcnt(0)"
                     : "+v"(bf[0]), "+v"(bf[1]), "+v"(bf[2]), "+v"(bf[3]) :: "memory");
#pragma unroll
        for (int nt = 4; nt < 8; nt++)
#pragma unroll
            for (int mt = 0; mt < 5; mt++)
                acc[mt][nt] = __builtin_amdgcn_mfma_f32_16x16x32_bf16(af[mt], bf[nt - 4], acc[mt][nt], 0, 0, 0);

        // write next chunk into the other buffer (its reads finished before this barrier)
        if (have) {
            const int jj = (it + 1) & 1;
            *(short8*)(Sb + jj * 10240 + tid * 16) = aS0;
            if (tid < 128) *(short8*)(Sb + jj * 10240 + (512 + tid) * 16) = aS1;
            char* Bp = Sb + 20480 + jj * 32768;
            *(short8*)(Bp + (0 * 512 + tid) * 16) = bS0;
            *(short8*)(Bp + (1 * 512 + tid) * 16) = bS1;
            *(short8*)(Bp + (2 * 512 + tid) * 16) = bS2;
            *(short8*)(Bp + (3 * 512 + tid) * 16) = bS3;
        }
    }

    // ---- epilogue: bias + LayerNorm + fp8 store via byte LDS tile ----
    float bcol[8], gcol[8], shcol[8];
#pragma unroll
    for (int nt = 0; nt < 8; nt++) {
        int col = ng * 128 + nt * 16 + l15;
        bcol[nt]  = b2f(bia[col]);
        gcol[nt]  = b2f(gg[col]);
        shcol[nt] = b2f(sh[col]);
    }
#pragma unroll
    for (int mt = 0; mt < 5; mt++)
#pragma unroll
        for (int nt = 0; nt < 8; nt++)
#pragma unroll
            for (int r = 0; r < 4; r++) acc[mt][nt][r] += bcol[nt];

#pragma unroll
    for (int mt = 0; mt < 5; mt++)
#pragma unroll
        for (int r = 0; r < 4; r++) {
            float s = 0.f, q = 0.f;
#pragma unroll
            for (int nt = 0; nt < 8; nt++) { float x = acc[mt][nt][r]; s += x; q += x * x; }
#pragma unroll
            for (int off = 1; off < 16; off <<= 1) {
                s += __shfl_xor(s, off, 64);
                q += __shfl_xor(q, off, 64);
            }
            if (l15 == 0) {
                int row = mg * 80 + mt * 16 + aq * 4 + r;
                red[row][ng][0] = s;
                red[row][ng][1] = q;
            }
        }
    __syncthreads();   // red complete; also: all K-loop LDS reads done -> S reusable

    float mean_[5][4], rstd_[5][4];
#pragma unroll
    for (int mt = 0; mt < 5; mt++)
#pragma unroll
        for (int r = 0; r < 4; r++) {
            int row = mg * 80 + mt * 16 + aq * 4 + r;
            float s = red[row][0][0] + red[row][1][0] + red[row][2][0] + red[row][3][0];
            float q = red[row][0][1] + red[row][1][1] + red[row][2][1] + red[row][3][1];
            float mu  = s * (1.f / 512.f);
            float var = q * (1.f / 512.f) - mu * mu;
            mean_[mt][r] = mu;
            rstd_[mt][r] = rsqrtf(var + 1e-5f);
        }

    // fp8 values -> 160x528 byte tile (stride 528 = 16B-aligned), then coalesced stores
    unsigned char* ot8 = (unsigned char*)S;
#pragma unroll
    for (int mt = 0; mt < 5; mt++)
#pragma unroll
        for (int nt = 0; nt < 8; nt++)
#pragma unroll
            for (int r = 0; r < 4; r++) {
                int row = mg * 80 + mt * 16 + aq * 4 + r;
                int col = ng * 128 + nt * 16 + l15;
                float v = (acc[mt][nt][r] - mean_[mt][r]) * rstd_[mt][r] * gcol[nt] + shcol[nt];
                ot8[row * 528 + col] = f2fp8(v);
            }
    __syncthreads();

    unsigned char* obase = a12 + sel * 512;
#pragma unroll
    for (int u = 0; u < 10; u++) {
        int ci  = u * 512 + tid;             // 5120 chunks of 16 fp8
        int row = ci >> 5, cc = (ci & 31) * 16;
        int gr  = r0 + row;
        if (gr < M_ROWS) {
            uint4 vch = *(const uint4*)(ot8 + row * 528 + cc);
            *(uint4*)(obase + (size_t)gr * 1024 + cc) = vch;
        }
    }
}

// ---------------- per-edge: fp8 gather, packed-f16 Z dots, fused exp + segment sums ----
// FOUR edges per wave (2 per half-wave, computed back-to-back). All 8 row-gathers
// issued before any compute; W3/index loads amortized; paired float2 stores.
// R4 result: only ~2us gain over 2-edge -> edge sits near the random-gather L2/L3
// service ceiling (~148MB at ~3.2 TB/s); parked.
__global__ __launch_bounds__(256) void edge_k(
    const unsigned char* __restrict__ a12,   // fp8 rows: 1024 B/node
    const int* __restrict__ eidx,            // (B, 2, E)
    const unsigned short* __restrict__ W3h,  // f16[512]
    const unsigned short* __restrict__ W4,
    const unsigned short* __restrict__ b4p,
    float* __restrict__ Vij, float* __restrict__ Vji,
    float* __restrict__ sumI, float* __restrict__ sumJ)
{
    int wid   = (blockIdx.x * 256 + threadIdx.x) >> 6;  // wave id: 4 edges/wave
    int lane  = threadIdx.x & 63;
    int which = lane >> 5;                              // 0/1: edge-pair within wave
    int l     = lane & 31;
    int e0    = wid * 4 + which * 2;                    // this half-wave: edges e0, e0+1
    // grid is exact (BE/4 waves); e0, e0+1 never straddle the batch boundary (EE even)
    int b  = e0 / EE, ei = e0 - b * EE;
    const int* ebase = eidx + b * 2 * EE;
    int srcA = ebase[ei],      srcB = ebase[ei + 1];
    int dstA = ebase[EE + ei], dstB = ebase[EE + ei + 1];
    const unsigned char* nb = a12 + (size_t)(b * NN) * 1024;
    const unsigned char* rsA = nb + (size_t)srcA * 1024;
    const unsigned char* rdA = nb + (size_t)dstA * 1024;
    const unsigned char* rsB = nb + (size_t)srcB * 1024;
    const unsigned char* rdB = nb + (size_t)dstB * 1024;
    int o = l * 16;                                     // 16 fp8 elems per lane/vector

    // issue all 8 gathers (4/edge x 2 edges) up front: 2x MLP
    uint4 u1sA = *(const uint4*)(rsA + o);
    uint4 u2sA = *(const uint4*)(rsA + 512 + o);
    uint4 u1dA = *(const uint4*)(rdA + o);
    uint4 u2dA = *(const uint4*)(rdA + 512 + o);
    uint4 u1sB = *(const uint4*)(rsB + o);
    uint4 u2sB = *(const uint4*)(rsB + 512 + o);
    uint4 u1dB = *(const uint4*)(rdB + o);
    uint4 u2dB = *(const uint4*)(rdB + 512 + o);
    uint4 w3a = *(const uint4*)(W3h + l * 16);          // 16 f16 = 32B
    uint4 w3b = *(const uint4*)(W3h + l * 16 + 8);

    const unsigned int W3W[8] = {w3a.x, w3a.y, w3a.z, w3a.w, w3b.x, w3b.y, w3b.z, w3b.w};
    const half2v HZ = {(_Float16)0.f, (_Float16)0.f};

    float zijA = 0.f, zjiA = 0.f, zijB = 0.f, zjiB = 0.f;
#define EDGE_STEP(ZI, ZJ, V1S, V2S, V1D, V2D, WI, C, SEL)            \
    {                                                                \
        half2v wv  = uint2h2(W3W[WI]);                               \
        half2v x1s = CVT8H(V1S.C, SEL);                              \
        half2v x2s = CVT8H(V2S.C, SEL);                              \
        half2v x1d = CVT8H(V1D.C, SEL);                              \
        half2v x2d = CVT8H(V2D.C, SEL);                              \
        half2v pij = __builtin_elementwise_max(x1s + x2d, HZ);       \
        half2v pji = __builtin_elementwise_max(x1d + x2s, HZ);       \
        ZI = FDOT2(pij, wv, ZI);                                     \
        ZJ = FDOT2(pji, wv, ZJ);                                     \
    }
#define EDGE_ALL(ZI, ZJ, V1S, V2S, V1D, V2D)                         \
    EDGE_STEP(ZI, ZJ, V1S, V2S, V1D, V2D, 0, x, false)               \
    EDGE_STEP(ZI, ZJ, V1S, V2S, V1D, V2D, 1, x, true)                \
    EDGE_STEP(ZI, ZJ, V1S, V2S, V1D, V2D, 2, y, false)               \
    EDGE_STEP(ZI, ZJ, V1S, V2S, V1D, V2D, 3, y, true)                \
    EDGE_STEP(ZI, ZJ, V1S, V2S, V1D, V2D, 4, z, false)               \
    EDGE_STEP(ZI, ZJ, V1S, V2S, V1D, V2D, 5, z, true)                \
    EDGE_STEP(ZI, ZJ, V1S, V2S, V1D, V2D, 6, w, false)               \
    EDGE_STEP(ZI, ZJ, V1S, V2S, V1D, V2D, 7, w, true)

    EDGE_ALL(zijA, zjiA, u1sA, u2sA, u1dA, u2dA)
    EDGE_ALL(zijB, zjiB, u1sB, u2sB, u1dB, u2dB)
#undef EDGE_ALL
#undef EDGE_STEP

#pragma unroll
    for (int off = 16; off >= 1; off >>= 1) {           // reduce within each half-wave
        zijA += __shfl_xor(zijA, off, 64);
        zjiA += __shfl_xor(zjiA, off, 64);
        zijB += __shfl_xor(zijB, off, 64);
        zjiB += __shfl_xor(zjiB, off, 64);
    }
    if (l == 0) {                                       // lanes 0 and 32: one pair each
        float w4f = b2f(W4[0]);
        float b4f = b2f(b4p[0]);
        float dA   = zijA - zjiA;                       // b3 cancels exactly
        float vijA = fmaf(dA, w4f, b4f);  vijA = vijA > 0.f ? vijA : 0.f;
        float vjiA = fmaf(-dA, w4f, b4f); vjiA = vjiA > 0.f ? vjiA : 0.f;
        float dB   = zijB - zjiB;
        float vijB = fmaf(dB, w4f, b4f);  vijB = vijB > 0.f ? vijB : 0.f;
        float vjiB = fmaf(-dB, w4f, b4f); vjiB = vjiB > 0.f ? vjiB : 0.f;
        float eijA = expf(vijA), ejiA = expf(vjiA);
        float eijB = expf(vijB), ejiB = expf(vjiB);
        *(float2*)(Vij + e0) = (float2){eijA, eijB};    // e0 even -> aligned
        *(float2*)(Vji + e0) = (float2){ejiA, ejiB};
        atomicAdd(sumI + b * NN + srcA, eijA);
        atomicAdd(sumJ + b * NN + dstA, ejiA);
        atomicAdd(sumI + b * NN + srcB, eijB);
        atomicAdd(sumJ + b * NN + dstB, ejiB);
    }
}

// ---------------- softmax final: normalize -> bf16 or f32 out ----------------
__global__ __launch_bounds__(256) void norm_k(
    const float* __restrict__ V, const int* __restrict__ eidx,
    const float* __restrict__ sumI, const float* __restrict__ sumJ,
    const int* __restrict__ flag, void* __restrict__ out)
{
    int i = blockIdx.x * 256 + threadIdx.x;
    if (i >= 2 * BE) return;
    int seg; const float* sm;
    if (i < BE) {
        int b = i / EE, e = i - b * EE;
        seg = b * NN + eidx[b * 2 * EE + e];
        sm = sumI;
    } else {
        int j = i - BE;
        int b = j / EE, e = j - b * EE;
        seg = b * NN + eidx[b * 2 * EE + EE + e];
        sm = sumJ;
    }
    float v = V[i] / sm[seg];
    if (*flag) ((float*)out)[i] = v;
    else       ((unsigned short*)out)[i] = f2b(v);
}

extern "C" void kernel_launch(void* const* d_in, const int* in_sizes, int n_in,
                              void* d_out, int out_size, void* d_ws, size_t ws_size,
                              hipStream_t stream)
{
    (void)in_sizes; (void)n_in; (void)out_size; (void)ws_size;
    const void* X_raw = d_in[0];
    const int*  eix   = (const int*)d_in[1];
    const void* W1    = d_in[3];
    const void* b1    = d_in[4];
    const void* g1    = d_in[5];
    const void* bb1   = d_in[6];
    const void* W2    = d_in[7];
    const void* b2    = d_in[8];
    const void* g2    = d_in[9];
    const void* bb2   = d_in[10];
    const void* W3    = d_in[11];
    const void* W4    = d_in[13];
    const void* b4    = d_in[14];

    char* ws = (char*)d_ws;
    size_t off = 0;
    int* flag = (int*)(ws + off);                        off += 16;
    unsigned char*  a12 = (unsigned char*)(ws + off);    off += (size_t)M_ROWS * 1024;     // 20.48 MB fp8
    unsigned short* Xb  = (unsigned short*)(ws + off);   off += (size_t)M_PAD * 512 * 2;   // 20.6 MB
    unsigned short* T1  = (unsigned short*)(ws + off);   off += (size_t)512 * 512 * 2;
    unsigned short* T2  = (unsigned short*)(ws + off);   off += (size_t)512 * 512 * 2;
    unsigned short* P   = (unsigned short*)(ws + off);   off += 16384;                     // params + f16 W3
    float* Vbuf = (float*)(ws + off);                    off += (size_t)2 * BE * 4;
    float* Z    = (float*)(ws + off);                    off += (size_t)2 * BNN * 4;
    float* sumI = Z;
    float* sumJ = Z + BNN;

    prep_k<<<PREP_NB, 256, 0, stream>>>(X_raw, W1, W2, b1, g1, bb1, b2, g2, bb2,
                                        W3, W4, b4, flag, Xb, T1, T2, P, Z);
    gemm_ln11_k<<<dim3(126, 2), 512, 0, stream>>>((const unsigned short*)X_raw, Xb, flag,
                                                  T1, T2,
                                                  P, P + 512, P + 1024,
                                                  P + 1536, P + 2048, P + 2560, a12);
    edge_k<<<BE / 16, 256, 0, stream>>>(a12, eix, P + 3600, P + 3584, P + 3585,
                                        Vbuf, Vbuf + BE, sumI, sumJ);
    norm_k<<<(2 * BE + 255) / 256, 256, 0, stream>>>(Vbuf, eix, sumI, sumJ, flag, (unsigned short*)d_out);
}